// Round 4
// baseline (299.657 us; speedup 1.0000x reference)
//
#include <hip/hip_runtime.h>

#define IH 126
#define IW 126
#define HW 15876      // 126*126
#define OH 124
#define OW 124
#define OHW 15376     // 124*124

// ---------------------------------------------------------------- conv_in
__global__ __launch_bounds__(256) void conv_in_kernel(
    const float* __restrict__ x, const float* __restrict__ w,
    const float* __restrict__ b, float* __restrict__ y)
{
  int pix = blockIdx.x * 256 + threadIdx.x;
  if (pix >= HW) return;
  int oc = blockIdx.y;                 // wave-uniform -> weights become s_loads
  int h  = pix / IW;
  int wc = pix - h * IW;
  const float* wp = w + oc * 27;
  float acc = b[oc];
#pragma unroll
  for (int ci = 0; ci < 3; ci++)
#pragma unroll
    for (int ky = 0; ky < 3; ky++)
#pragma unroll
      for (int kx = 0; kx < 3; kx++)
        acc = fmaf(x[ci * 128 * 128 + (h + ky) * 128 + (wc + kx)],
                   wp[ci * 9 + ky * 3 + kx], acc);
  y[oc * HW + pix] = acc;
}

// ---------------------------------------------------------------- involution v4
// v3 + bspan staged in LDS + fully-unrolled phase C (24 + tail) so the
// compiler can batch/prefetch the s_load_dwordx16 span-weight fetches.
__global__ __launch_bounds__(512, 4) void inv_kernel(
    const float* __restrict__ x, float* __restrict__ y,
    const float* __restrict__ wr, const float* __restrict__ br,
    const float* __restrict__ gam, const float* __restrict__ bet,
    const float* __restrict__ mu, const float* __restrict__ var,
    const float* __restrict__ wspan, const float* __restrict__ bspan)
{
  __shared__ __align__(16) float xs[140][68];   // 38,080 B; aliased by ob[64][33] in E
  __shared__ __align__(16) float wvs[6272];     // 25,088 B; tss = wvs[5632..]
  __shared__ float bsp_l[196];                  //    784 B
  float* tss = &wvs[5632];                      // [32][20]
  float* ob  = &xs[0][0];                       // [64][33] alias

  int tid = threadIdx.x;
  int bx = blockIdx.x & 15, by = blockIdx.x >> 4;
  int ox0 = bx * 8, oy0 = by * 4;
  int xh0 = ox0 - 3, yh0 = oy0 - 3;

  // ---- Phase A: stage x halo (14 cols x 10 rows x 64 ch) + bspan
  if (tid < 196) bsp_l[tid] = bspan[tid];
  for (int idx = tid; idx < 140 * 64; idx += 512) {
    int c = idx / 140;
    int pos = idx - c * 140;
    int row = pos / 14;
    int col = pos - row * 14;
    int gy = yh0 + row, gx = xh0 + col;
    float v = 0.f;
    if (gy >= 0 && gy < IH && gx >= 0 && gx < IW)
      v = x[c * HW + gy * IW + gx];
    xs[pos][c] = v;
  }
  __syncthreads();

  int w_ = __builtin_amdgcn_readfirstlane(tid >> 6);  // wave 0..7
  int ln = tid & 63;
  int p  = ln & 31;                   // pixel 0..31 (upper 32 lanes duplicate)
  int prow = p >> 3, pcol = p & 7;
  int pc = (prow + 3) * 14 + (pcol + 3);

  // ---- Phase B: t = ReLU(BN(Wr.x)); wave w_ does cr = 2w_, 2w_+1 (uniform)
  {
    int cr0 = 2 * w_;
    const float* wa = wr + cr0 * 64;  // uniform -> s_load
    const float* wb = wa + 64;
    float a0 = 0.f, a1 = 0.f;
#pragma unroll
    for (int ci = 0; ci < 64; ci += 4) {
      float4 xv = *(const float4*)&xs[pc][ci];
      a0 = fmaf(xv.x, wa[ci + 0], a0); a1 = fmaf(xv.x, wb[ci + 0], a1);
      a0 = fmaf(xv.y, wa[ci + 1], a0); a1 = fmaf(xv.y, wb[ci + 1], a1);
      a0 = fmaf(xv.z, wa[ci + 2], a0); a1 = fmaf(xv.z, wb[ci + 2], a1);
      a0 = fmaf(xv.w, wa[ci + 3], a0); a1 = fmaf(xv.w, wb[ci + 3], a1);
    }
    float s0 = gam[cr0]     * rsqrtf(var[cr0]     + 1e-5f);
    float s1 = gam[cr0 + 1] * rsqrtf(var[cr0 + 1] + 1e-5f);
    float t0 = (a0 + br[cr0]     - mu[cr0])     * s0 + bet[cr0];
    float t1 = (a1 + br[cr0 + 1] - mu[cr0 + 1]) * s1 + bet[cr0 + 1];
    if (ln < 32) {
      tss[p * 20 + cr0]     = fmaxf(t0, 0.f);
      tss[p * 20 + cr0 + 1] = fmaxf(t1, 0.f);
    }
  }
  __syncthreads();

  // ---- Phase C: span. wave w_ owns uniform pairs (g*49+k) = w_ + 8j.
  {
    float tv[16];
#pragma unroll
    for (int i = 0; i < 4; i++) {
      float4 t4 = *(const float4*)&tss[p * 20 + 4 * i];
      tv[4 * i] = t4.x; tv[4 * i + 1] = t4.y;
      tv[4 * i + 2] = t4.z; tv[4 * i + 3] = t4.w;
    }
    __syncthreads();                   // tss reads done; tail may be overwritten
#pragma unroll
    for (int j = 0; j < 24; j++) {
      int pair = w_ + 8 * j;           // wave-uniform, always < 192+8
      const float* wk = wspan + pair * 16;   // uniform -> s_load_dwordx16
      float a = bsp_l[pair];
#pragma unroll
      for (int i = 0; i < 16; i++) a = fmaf(tv[i], wk[i], a);
      if (ln < 32) wvs[pair * 32 + pcol * 4 + prow] = a;
    }
    if (w_ < 4) {                      // tail: pair = 192..195
      int pair = w_ + 192;
      const float* wk = wspan + pair * 16;
      float a = bsp_l[pair];
#pragma unroll
      for (int i = 0; i < 16; i++) a = fmaf(tv[i], wk[i], a);
      if (ln < 32) wvs[pair * 32 + pcol * 4 + prow] = a;
    }
  }
  __syncthreads();

  // ---- Phase D: einsum. wave = output column w_, lane = channel.
  float acc0 = 0.f, acc1 = 0.f, acc2 = 0.f, acc3 = 0.f;
  {
    int c = ln;
    int g = ln >> 4;
    float xw[4][7];
#pragma unroll
    for (int r = 0; r < 4; r++)
#pragma unroll
      for (int kx = 0; kx < 7; kx++)
        xw[r][kx] = xs[r * 14 + w_ + kx][c];   // uniform base + lane: conflict-free
#pragma unroll
    for (int ky = 0; ky < 7; ky++) {
      if (ky > 0) {
#pragma unroll
        for (int r = 0; r < 3; r++)
#pragma unroll
          for (int kx = 0; kx < 7; kx++) xw[r][kx] = xw[r + 1][kx];
#pragma unroll
        for (int kx = 0; kx < 7; kx++)
          xw[3][kx] = xs[(ky + 3) * 14 + w_ + kx][c];
      }
#pragma unroll
      for (int kx = 0; kx < 7; kx++) {
        int k = ky * 7 + kx;
        float4 w4 = *(const float4*)&wvs[(g * 49 + k) * 32 + w_ * 4];
        acc0 = fmaf(w4.x, xw[0][kx], acc0);
        acc1 = fmaf(w4.y, xw[1][kx], acc1);
        acc2 = fmaf(w4.z, xw[2][kx], acc2);
        acc3 = fmaf(w4.w, xw[3][kx], acc3);
      }
    }
  }
  __syncthreads();                     // xs reads done; safe to alias with ob

  // ---- Phase E: transpose via LDS, coalesced store (+outer ReLU)
  {
    int c = ln;
    ob[c * 33 + 0 * 8 + w_] = fmaxf(acc0, 0.f);
    ob[c * 33 + 1 * 8 + w_] = fmaxf(acc1, 0.f);
    ob[c * 33 + 2 * 8 + w_] = fmaxf(acc2, 0.f);
    ob[c * 33 + 3 * 8 + w_] = fmaxf(acc3, 0.f);
  }
  __syncthreads();
  for (int j = tid; j < 2048; j += 512) {
    int c2 = j >> 5, pp = j & 31;
    int pr = pp >> 3, pc2 = pp & 7;
    int gy = oy0 + pr, gx = ox0 + pc2;
    if (gy < IH && gx < IW)
      y[c2 * HW + gy * IW + gx] = ob[c2 * 33 + pp];
  }
}

// ---------------------------------------------------------------- conv_out prep
// w (128,64,3,3) -> wt2[oc>>1][ky][ci][kx][oc&1]: each wave's 2-oc slab is a
// contiguous 4.6 KB run -> compiler batches s_load_dwordx8/x16 prefetches.
__global__ __launch_bounds__(256) void transpose_w_kernel(
    const float* __restrict__ w, float* __restrict__ wt2)
{
  int i = blockIdx.x * 256 + threadIdx.x;
  if (i >= 128 * 64 * 9) return;
  int oc = i / 576;
  int rem = i - oc * 576;
  int ci = rem / 9;
  int k = rem - ci * 9;
  int ky = k / 3, kx = k - ky * 3;
  wt2[(oc >> 1) * 1152 + ky * 384 + ci * 6 + kx * 2 + (oc & 1)] = w[i];
}

// ---------------------------------------------------------------- conv_out v4
// Register-blocked, NO LDS: 4 px (horizontal, kx-sliding window) x 2 oc per
// thread. Each weight dword feeds 4 FMAs, each x dword ~8 -> scalar-cache
// demand drops 4x vs v3; x comes from L1/L2 via coalesced float2.
// Grid (64 tiles 16x16, 16 oc-groups) x 256 thr = 16 waves/CU.
__global__ __launch_bounds__(256) void conv_out_kernel(
    const float* __restrict__ x, const float* __restrict__ wt2,
    const float* __restrict__ b, float* __restrict__ y)
{
  int tid = threadIdx.x;
  int wv_ = __builtin_amdgcn_readfirstlane(tid >> 6);   // wave 0..3
  int ln = tid & 63;
  int tx = blockIdx.x & 7, ty = blockIdx.x >> 3;
  int oc0 = blockIdx.y * 8 + wv_ * 2;                   // wave-uniform

  int row  = ty * 16 + (ln >> 2);
  int col0 = tx * 16 + (ln & 3) * 4;
  bool valid = (row < OH) && (col0 < OW);
  int r0 = valid ? row : 0;
  int c0 = valid ? col0 : 0;

  const float* wb = wt2 + oc0 * 576;                    // (oc0>>1)*1152
  float acc0[4], acc1[4];
  float bb0 = b[oc0], bb1 = b[oc0 + 1];
#pragma unroll
  for (int i = 0; i < 4; i++) { acc0[i] = bb0; acc1[i] = bb1; }

  for (int ky = 0; ky < 3; ky++) {
    const float* xr = x + (r0 + ky) * IW + c0;
    const float* wk = wb + ky * 384;
#pragma unroll 8
    for (int ci = 0; ci < 64; ci++) {
      const float* xp = xr + ci * HW;
      float2 u0 = *(const float2*)(xp);      // even-dword offset: 8B aligned
      float2 u1 = *(const float2*)(xp + 2);
      float2 u2 = *(const float2*)(xp + 4);
      float xv[6] = {u0.x, u0.y, u1.x, u1.y, u2.x, u2.y};
      const float* wc = wk + ci * 6;         // uniform -> s_loads
      float w00 = wc[0], w01 = wc[1];
      float w10 = wc[2], w11 = wc[3];
      float w20 = wc[4], w21 = wc[5];
#pragma unroll
      for (int px = 0; px < 4; px++) {
        float xa = xv[px], xb = xv[px + 1], xc = xv[px + 2];
        acc0[px] = fmaf(xa, w00, acc0[px]);
        acc1[px] = fmaf(xa, w01, acc1[px]);
        acc0[px] = fmaf(xb, w10, acc0[px]);
        acc1[px] = fmaf(xb, w11, acc1[px]);
        acc0[px] = fmaf(xc, w20, acc0[px]);
        acc1[px] = fmaf(xc, w21, acc1[px]);
      }
    }
  }

  if (valid) {
    float4 s0 = make_float4(acc0[0], acc0[1], acc0[2], acc0[3]);
    float4 s1 = make_float4(acc1[0], acc1[1], acc1[2], acc1[3]);
    *(float4*)&y[oc0 * OHW + row * OW + col0] = s0;
    *(float4*)&y[(oc0 + 1) * OHW + row * OW + col0] = s1;
  }
}

// ---------------------------------------------------------------- launch
extern "C" void kernel_launch(void* const* d_in, const int* in_sizes, int n_in,
                              void* d_out, int out_size, void* d_ws, size_t ws_size,
                              hipStream_t stream)
{
  const float* input = (const float*)d_in[0];
  const float* ciw   = (const float*)d_in[1];
  const float* cib   = (const float*)d_in[2];
  const float* wred  = (const float*)d_in[3];
  const float* bred  = (const float*)d_in[4];
  const float* gam   = (const float*)d_in[5];
  const float* bet   = (const float*)d_in[6];
  const float* mu    = (const float*)d_in[7];
  const float* var   = (const float*)d_in[8];
  const float* wspan = (const float*)d_in[9];
  const float* bspan = (const float*)d_in[10];
  const float* cow   = (const float*)d_in[11];
  const float* cob   = (const float*)d_in[12];
  float* out = (float*)d_out;

  float* bufA = (float*)d_ws;                 // 64*126*126 = 1,016,064 floats
  float* bufB = bufA + (1 << 20);             // @ 4 MiB
  float* wt   = bufA + (1 << 21);             // @ 8 MiB, 73,728 floats

  transpose_w_kernel<<<288, 256, 0, stream>>>(cow, wt);
  conv_in_kernel<<<dim3(63, 64), 256, 0, stream>>>(input, ciw, cib, bufA);

  float* cur = bufA; float* nxt = bufB;
  for (int i = 0; i < 6; i++) {
    inv_kernel<<<512, 512, 0, stream>>>(cur, nxt,
        wred + i * 16 * 64, bred + i * 16, gam + i * 16, bet + i * 16,
        mu + i * 16, var + i * 16, wspan + i * 196 * 16, bspan + i * 196);
    float* t = cur; cur = nxt; nxt = t;
  }
  conv_out_kernel<<<dim3(64, 16), 256, 0, stream>>>(cur, wt, cob, out);
}